// Round 1
// baseline (261.876 us; speedup 1.0000x reference)
//
#include <hip/hip_runtime.h>
#include <hip/hip_bf16.h>
#include <math.h>

#define NLAT 255
#define LMAX 96
#define MMAX 96
#define BC   256
#define NPIX 49152

// ---------------- ring geometry (NSIDE=64, compile-time closed forms) -------
__device__ __forceinline__ void ring_params(int t, int& n, int& roff) {
    if (t < 63)        { n = 4 * (t + 1); roff = 2 * t * (t + 1); }
    else if (t <= 191) { n = 256;         roff = 8064 + 256 * (t - 63); }
    else               { int w = 255 - t; n = 4 * w; roff = 49152 - 2 * w * (w + 1); }
}

// ---------------- kernel 1: transpose x[bc][l][m] -> xT[m][l][bc] -----------
__global__ __launch_bounds__(256) void k_transpose(
        const float* __restrict__ xr, const float* __restrict__ xi,
        float* __restrict__ xTr, float* __restrict__ xTi) {
    __shared__ float tile[32][33];
    const int l   = blockIdx.x;          // 0..95
    const int bc0 = blockIdx.y * 32;     // 0..224
    const int z   = blockIdx.z;          // 0..5
    const int comp = z / 3;
    const int m0   = (z % 3) * 32;
    const float* in  = comp ? xi : xr;
    float*       out = comp ? xTi : xTr;
    const int tx = threadIdx.x;          // 0..31
    const int ty = threadIdx.y;          // 0..7
#pragma unroll
    for (int j = 0; j < 4; ++j) {
        int bcl = ty + j * 8;
        tile[bcl][tx] = in[((bc0 + bcl) * 96 + l) * 96 + m0 + tx];
    }
    __syncthreads();
#pragma unroll
    for (int j = 0; j < 4; ++j) {
        int ml = ty + j * 8;
        out[((m0 + ml) * 96 + l) * 256 + bc0 + tx] = tile[tx][ml];
    }
}

// ---------------- kernel 2: Legendre contraction + phase --------------------
// X[t][m][bc] (interleaved re,im as float2) = e^{i off[t,m]} * sum_l pct[m,l,t] * x[bc,l,m]
__global__ __launch_bounds__(256) void k_legendre(
        const float* __restrict__ xTr, const float* __restrict__ xTi,
        const float* __restrict__ pct, const float* __restrict__ off,
        float2* __restrict__ X) {
    __shared__ float pcts[96 * 32];
    const int m  = blockIdx.x;        // 0..95
    const int t0 = blockIdx.y * 32;   // 0..224
    const int tid = threadIdx.x;      // bc

    for (int idx = tid; idx < 96 * 32; idx += 256) {
        int l = idx >> 5, tt = idx & 31;
        int t = t0 + tt;
        pcts[idx] = (t < NLAT) ? pct[(m * 96 + l) * NLAT + t] : 0.f;
    }
    __syncthreads();

    float accR[32], accI[32];
#pragma unroll
    for (int i = 0; i < 32; ++i) { accR[i] = 0.f; accI[i] = 0.f; }

    for (int l = 0; l < 96; ++l) {
        float xr = xTr[(m * 96 + l) * 256 + tid];
        float xi = xTi[(m * 96 + l) * 256 + tid];
        const float4* pv4 = (const float4*)&pcts[l * 32];
#pragma unroll
        for (int q = 0; q < 8; ++q) {
            float4 pv = pv4[q];
            accR[q*4+0] = fmaf(pv.x, xr, accR[q*4+0]); accI[q*4+0] = fmaf(pv.x, xi, accI[q*4+0]);
            accR[q*4+1] = fmaf(pv.y, xr, accR[q*4+1]); accI[q*4+1] = fmaf(pv.y, xi, accI[q*4+1]);
            accR[q*4+2] = fmaf(pv.z, xr, accR[q*4+2]); accI[q*4+2] = fmaf(pv.z, xi, accI[q*4+2]);
            accR[q*4+3] = fmaf(pv.w, xr, accR[q*4+3]); accI[q*4+3] = fmaf(pv.w, xi, accI[q*4+3]);
        }
    }

#pragma unroll
    for (int tt = 0; tt < 32; ++tt) {
        int t = t0 + tt;
        if (t < NLAT) {
            float o = off[t * 96 + m];
            float so, co;
            __sincosf(o, &so, &co);
            float r = accR[tt] * co - accI[tt] * so;
            float i = accR[tt] * so + accI[tt] * co;
            X[(t * 96 + m) * 256 + tid] = make_float2(r, i);
        }
    }
}

// ---------------- kernel 3: per-ring direct inverse real DFT ----------------
// y[p] = sum_{m=0}^{min(95, n/2)} scale_m * (Xr cos(2pi m p/n) - Xi sin(2pi m p/n))
// scale_m = 1 for m=0 and m=n/2 (DC/Nyquist, imag dropped via s=0), else 2.
__global__ __launch_bounds__(256) void k_dft(
        const float2* __restrict__ X, float* __restrict__ out) {
    __shared__ float2 xs[96][32];
    const int t   = blockIdx.x;        // 0..254
    const int bc0 = blockIdx.y * 32;   // bc tile
    const int tid = threadIdx.x;

    int n, roff;
    ring_params(t, n, roff);
    const int half = n >> 1;

    for (int idx = tid; idx < 96 * 32; idx += 256) {
        int m = idx >> 5, b = idx & 31;
        float2 v = X[(t * 96 + m) * 256 + bc0 + b];
        float sc = (m == 0 || m == half) ? 1.f : 2.f;
        xs[m][b] = make_float2(v.x * sc, v.y * sc);
    }
    __syncthreads();

    const int p = tid;
    if (p < n) {
        const int mtop = min(95, half);
        float delta = (float)p * (6.28318530717958647692f / (float)n);
        float cd, sd;
        __sincosf(delta, &sd, &cd);
        float c = 1.f, s = 0.f;
        float y[32];
#pragma unroll
        for (int b = 0; b < 32; ++b) y[b] = 0.f;

        for (int m = 0; m <= mtop; ++m) {
#pragma unroll
            for (int q = 0; q < 16; ++q) {
                float4 v = *(const float4*)&xs[m][q * 2];   // (r0,i0,r1,i1)
                y[2*q]   = fmaf(v.x,  c, y[2*q]);
                y[2*q]   = fmaf(v.y, -s, y[2*q]);
                y[2*q+1] = fmaf(v.z,  c, y[2*q+1]);
                y[2*q+1] = fmaf(v.w, -s, y[2*q+1]);
            }
            float cn = c * cd - s * sd;
            s = s * cd + c * sd;
            c = cn;
        }

        const int base = roff + p;
#pragma unroll
        for (int b = 0; b < 32; ++b) {
            out[(bc0 + b) * NPIX + base] = y[b];
        }
    }
}

// ---------------- launcher --------------------------------------------------
extern "C" void kernel_launch(void* const* d_in, const int* in_sizes, int n_in,
                              void* d_out, int out_size, void* d_ws, size_t ws_size,
                              hipStream_t stream) {
    const float* xr  = (const float*)d_in[0];   // (4,64,96,96)
    const float* xi  = (const float*)d_in[1];   // (4,64,96,96)
    const float* pct = (const float*)d_in[2];   // (96,96,255)
    const float* off = (const float*)d_in[3];   // (255,96)
    float* out = (float*)d_out;                 // (4,64,49152)

    float* ws  = (float*)d_ws;
    float* xTr = ws;                        // 96*96*256 = 2359296 floats
    float* xTi = ws + 2359296;              // 2359296 floats
    float2* X  = (float2*)(ws + 4718592);   // 255*96*256 float2 = 50.1 MB

    k_transpose<<<dim3(96, 8, 6), dim3(32, 8), 0, stream>>>(xr, xi, xTr, xTi);
    k_legendre<<<dim3(96, 8), 256, 0, stream>>>(xTr, xTi, pct, off, X);
    k_dft<<<dim3(NLAT, 8), 256, 0, stream>>>(X, out);
}